// Round 5
// baseline (580.040 us; speedup 1.0000x reference)
//
#include <hip/hip_runtime.h>
#include <hip/hip_bf16.h>

// GraphConv x2 via dst-sorted CSR gather (no float atomics):
//   gather1: aggm = mean_e w*x[src]
//   nodeAB:  h  = sigmoid(aggm@Wrel1^T + b1 + x@Wroot1^T)   (h stays in regs)
//            hr = h@Wrel2^T ; hro = h@Wroot2^T + b2
//   gather2: out = mean_e w*hr[src] + hro
// CSR build: hist -> scan -> bucketed two-pass placement (no 8x write amp).

#define NF 64

// ---------------- dtype detection (int64 vs int32 edge_index) ---------------
__global__ void detect_i64(const unsigned* __restrict__ raw, int* __restrict__ flag, int E) {
    __shared__ unsigned red[256];
    unsigned v = 0;
    int lim = (E < 4096) ? E : 4096;
    for (int i = threadIdx.x; i < lim; i += 256) v |= raw[2 * i + 1];
    red[threadIdx.x] = v;
    __syncthreads();
    for (int s = 128; s > 0; s >>= 1) {
        if (threadIdx.x < s) red[threadIdx.x] |= red[threadIdx.x + s];
        __syncthreads();
    }
    if (threadIdx.x == 0) *flag = (red[0] == 0) ? 1 : 0;  // high dwords zero => int64
}

// ---------------- histogram of dst ------------------------------------------
__global__ __launch_bounds__(256) void hist(const void* __restrict__ raw,
                                            const int* __restrict__ flag,
                                            int* __restrict__ deg, int E) {
    int e = blockIdx.x * blockDim.x + threadIdx.x;
    if (e >= E) return;
    int d = (*flag) ? (int)((const long long*)raw)[E + e] : ((const int*)raw)[E + e];
    atomicAdd(&deg[d], 1);
}

// ---------------- exclusive scan (3 kernels) ---------------------------------
__global__ __launch_bounds__(1024) void scan_k1(const int* __restrict__ deg,
                                                int* __restrict__ base,
                                                int* __restrict__ bsums, int N) {
    __shared__ int tmp[1024];
    int tid = threadIdx.x;
    int i = blockIdx.x * 1024 + tid;
    int v = (i < N) ? deg[i] : 0;
    tmp[tid] = v;
    __syncthreads();
    for (int off = 1; off < 1024; off <<= 1) {
        int t = (tid >= off) ? tmp[tid - off] : 0;
        __syncthreads();
        tmp[tid] += t;
        __syncthreads();
    }
    if (i < N) base[i] = tmp[tid] - v;
    if (tid == 1023) bsums[blockIdx.x] = tmp[tid];
}

__global__ __launch_bounds__(256) void scan_k2(int* __restrict__ bsums, int nb) {
    __shared__ int tmp[256];
    int tid = threadIdx.x;
    int v = (tid < nb) ? bsums[tid] : 0;
    tmp[tid] = v;
    __syncthreads();
    for (int off = 1; off < 256; off <<= 1) {
        int t = (tid >= off) ? tmp[tid - off] : 0;
        __syncthreads();
        tmp[tid] += t;
        __syncthreads();
    }
    if (tid < nb) bsums[tid] = tmp[tid] - v;
}

__global__ __launch_bounds__(1024) void scan_k3(int* __restrict__ base,
                                                const int* __restrict__ bsums,
                                                int* __restrict__ cursor, int N) {
    int i = blockIdx.x * 1024 + threadIdx.x;
    if (i >= N) return;
    int b = base[i] + bsums[blockIdx.x];
    base[i] = b;
    cursor[i] = b;
}

// ---------------- bucket cursors: bcur[b] = base[b*128] ----------------------
__global__ __launch_bounds__(256) void binit(const int* __restrict__ base,
                                             int* __restrict__ bcur, int nbuck) {
    int b = blockIdx.x * blockDim.x + threadIdx.x;
    if (b < nbuck) bcur[b] = base[b << 7];
}

// ---- pass 1: scatter edges to bucket-contiguous tmp slots (low write amp) ---
__global__ __launch_bounds__(256) void pass1_bucket(
    const void* __restrict__ raw, const int* __restrict__ flag,
    const float* __restrict__ ea, int* __restrict__ bcur,
    int2* __restrict__ tmpv, int* __restrict__ tmpd, int E)
{
    int e = blockIdx.x * blockDim.x + threadIdx.x;
    if (e >= E) return;
    int s, d;
    if (*flag) {
        const long long* p = (const long long*)raw;
        s = (int)p[e]; d = (int)p[E + e];
    } else {
        const int* p = (const int*)raw;
        s = p[e]; d = p[E + e];
    }
    int slot = atomicAdd(&bcur[d >> 7], 1);
    tmpv[slot] = make_int2(s, __float_as_int(ea[e]));
    tmpd[slot] = d;
}

// ---- pass 2: place within bucket (coalesced read, L2-local random write) ----
__global__ __launch_bounds__(256) void pass2_place(
    const int2* __restrict__ tmpv, const int* __restrict__ tmpd,
    int* __restrict__ cursor, int2* __restrict__ csr, int E)
{
    int sidx = blockIdx.x * blockDim.x + threadIdx.x;
    if (sidx >= E) return;
    int2 v = tmpv[sidx];
    int d = tmpd[sidx];
    int fin = atomicAdd(&cursor[d], 1);
    csr[fin] = v;
}

// ---------------- gather1: aggm[n] = (sum_e w*x[src])/max(deg,1) -------------
__global__ __launch_bounds__(256) void gather1(
    const float* __restrict__ x, const int2* __restrict__ csr,
    const int* __restrict__ base, const int* __restrict__ deg,
    float* __restrict__ aggm, int N)
{
    int lane = threadIdx.x & 63;
    int wid = blockIdx.x * 4 + (threadIdx.x >> 6);
    int stride = gridDim.x * 4;
    for (int n = wid; n < N; n += stride) {
        int b = __builtin_amdgcn_readfirstlane(base[n]);
        int dg = __builtin_amdgcn_readfirstlane(deg[n]);
        float acc0 = 0.f, acc1 = 0.f, acc2 = 0.f, acc3 = 0.f;
        int i = b, e = b + dg;
        for (; i + 8 <= e; i += 8) {
            int2 r0 = csr[i], r1 = csr[i + 1], r2 = csr[i + 2], r3 = csr[i + 3];
            int2 r4 = csr[i + 4], r5 = csr[i + 5], r6 = csr[i + 6], r7 = csr[i + 7];
            float v0 = x[(size_t)r0.x * 64 + lane];
            float v1 = x[(size_t)r1.x * 64 + lane];
            float v2 = x[(size_t)r2.x * 64 + lane];
            float v3 = x[(size_t)r3.x * 64 + lane];
            float v4 = x[(size_t)r4.x * 64 + lane];
            float v5 = x[(size_t)r5.x * 64 + lane];
            float v6 = x[(size_t)r6.x * 64 + lane];
            float v7 = x[(size_t)r7.x * 64 + lane];
            acc0 = fmaf(__int_as_float(r0.y), v0, acc0);
            acc1 = fmaf(__int_as_float(r1.y), v1, acc1);
            acc2 = fmaf(__int_as_float(r2.y), v2, acc2);
            acc3 = fmaf(__int_as_float(r3.y), v3, acc3);
            acc0 = fmaf(__int_as_float(r4.y), v4, acc0);
            acc1 = fmaf(__int_as_float(r5.y), v5, acc1);
            acc2 = fmaf(__int_as_float(r6.y), v6, acc2);
            acc3 = fmaf(__int_as_float(r7.y), v7, acc3);
        }
        for (; i + 4 <= e; i += 4) {
            int2 r0 = csr[i], r1 = csr[i + 1], r2 = csr[i + 2], r3 = csr[i + 3];
            acc0 = fmaf(__int_as_float(r0.y), x[(size_t)r0.x * 64 + lane], acc0);
            acc1 = fmaf(__int_as_float(r1.y), x[(size_t)r1.x * 64 + lane], acc1);
            acc2 = fmaf(__int_as_float(r2.y), x[(size_t)r2.x * 64 + lane], acc2);
            acc3 = fmaf(__int_as_float(r3.y), x[(size_t)r3.x * 64 + lane], acc3);
        }
        for (; i < e; ++i) {
            int2 r = csr[i];
            acc0 = fmaf(__int_as_float(r.y), x[(size_t)r.x * 64 + lane], acc0);
        }
        float inv = 1.0f / fmaxf((float)dg, 1.0f);
        aggm[(size_t)n * 64 + lane] = ((acc0 + acc1) + (acc2 + acc3)) * inv;
    }
}

// ---------------- nodeAB: fused node transform, h never hits global ----------
// phase 1: h = sigmoid(aggm@Wrel1^T + b1 + x@Wroot1^T)   (lane = feature)
// phase 2: hr = h@Wrel2^T (lanes 0..31), hro = h@Wroot2^T + b2 (lanes 32..63)
//          via wave-private LDS broadcast of the h-row.
__global__ __launch_bounds__(256) void nodeAB(
    const float* __restrict__ x, const float* __restrict__ aggm,
    const float* __restrict__ Wrel1, const float* __restrict__ brel1,
    const float* __restrict__ Wroot1,
    const float* __restrict__ Wrel2, const float* __restrict__ brel2,
    const float* __restrict__ Wroot2,
    float* __restrict__ hr, float* __restrict__ hro, int N)
{
    __shared__ float lh[4][64];
    int t = threadIdx.x;
    int lane = t & 63, wv = t >> 6;
    float* myl = lh[wv];
    const float* wrp = Wrel1 + (size_t)lane * 64;
    const float* wop = Wroot1 + (size_t)lane * 64;
    float bias1 = brel1[lane];
    int j = lane & 31;
    bool isRel = lane < 32;
    const float* wp2 = (isRel ? Wrel2 : Wroot2) + (size_t)j * 64;
    float bias2 = isRel ? 0.f : brel2[j];
    float* dst2 = isRel ? hr : hro;

    int wid = blockIdx.x * 4 + wv;
    int stride = gridDim.x * 4;
    for (int n0 = wid * 2; n0 < N; n0 += stride * 2) {
        int nA = __builtin_amdgcn_readfirstlane(n0);
        bool hasB = (n0 + 1) < N;
        int nB = __builtin_amdgcn_readfirstlane(hasB ? n0 + 1 : n0);
        const float* ar0 = aggm + (size_t)nA * 64;
        const float* xr0 = x + (size_t)nA * 64;
        const float* ar1 = aggm + (size_t)nB * 64;
        const float* xr1 = x + (size_t)nB * 64;
        float accr0 = bias1, acco0 = 0.f, accr1 = bias1, acco1 = 0.f;
#pragma unroll
        for (int c = 0; c < 16; ++c) {
            float4 w_r = *(const float4*)(wrp + 4 * c);
            float4 w_o = *(const float4*)(wop + 4 * c);
            float4 a0 = *(const float4*)(ar0 + 4 * c);
            float4 x0 = *(const float4*)(xr0 + 4 * c);
            float4 a1 = *(const float4*)(ar1 + 4 * c);
            float4 x1 = *(const float4*)(xr1 + 4 * c);
            accr0 = fmaf(a0.x, w_r.x, accr0); accr1 = fmaf(a1.x, w_r.x, accr1);
            accr0 = fmaf(a0.y, w_r.y, accr0); accr1 = fmaf(a1.y, w_r.y, accr1);
            accr0 = fmaf(a0.z, w_r.z, accr0); accr1 = fmaf(a1.z, w_r.z, accr1);
            accr0 = fmaf(a0.w, w_r.w, accr0); accr1 = fmaf(a1.w, w_r.w, accr1);
            acco0 = fmaf(x0.x, w_o.x, acco0); acco1 = fmaf(x1.x, w_o.x, acco1);
            acco0 = fmaf(x0.y, w_o.y, acco0); acco1 = fmaf(x1.y, w_o.y, acco1);
            acco0 = fmaf(x0.z, w_o.z, acco0); acco1 = fmaf(x1.z, w_o.z, acco1);
            acco0 = fmaf(x0.w, w_o.w, acco0); acco1 = fmaf(x1.w, w_o.w, acco1);
        }
        float h0 = 1.0f / (1.0f + __expf(-(accr0 + acco0)));
        float h1 = 1.0f / (1.0f + __expf(-(accr1 + acco1)));

        // phase 2, node A (wave-private LDS, no barrier needed)
        myl[lane] = h0;
        float acc = bias2;
#pragma unroll
        for (int c = 0; c < 16; ++c) {
            float4 hv = *(const float4*)(myl + 4 * c);   // broadcast read
            float4 w = *(const float4*)(wp2 + 4 * c);
            acc = fmaf(hv.x, w.x, acc);
            acc = fmaf(hv.y, w.y, acc);
            acc = fmaf(hv.z, w.z, acc);
            acc = fmaf(hv.w, w.w, acc);
        }
        dst2[(size_t)nA * 32 + j] = acc;

        // phase 2, node B
        if (hasB) {
            myl[lane] = h1;
            acc = bias2;
#pragma unroll
            for (int c = 0; c < 16; ++c) {
                float4 hv = *(const float4*)(myl + 4 * c);
                float4 w = *(const float4*)(wp2 + 4 * c);
                acc = fmaf(hv.x, w.x, acc);
                acc = fmaf(hv.y, w.y, acc);
                acc = fmaf(hv.z, w.z, acc);
                acc = fmaf(hv.w, w.w, acc);
            }
            dst2[(size_t)nB * 32 + j] = acc;
        }
    }
}

// ---------------- gather2 + epilogue: out = agg2/deg + hro -------------------
__global__ __launch_bounds__(256) void gather2(
    const float* __restrict__ hr, const float* __restrict__ hro,
    const int2* __restrict__ csr, const int* __restrict__ base,
    const int* __restrict__ deg, float* __restrict__ out, int N)
{
    int lane = threadIdx.x & 63;
    int j = lane & 31, half = lane >> 5;
    int wid = blockIdx.x * 4 + (threadIdx.x >> 6);
    int stride = gridDim.x * 4;
    for (int n = wid; n < N; n += stride) {
        int b = __builtin_amdgcn_readfirstlane(base[n]);
        int dg = __builtin_amdgcn_readfirstlane(deg[n]);
        float a0 = 0.f, a1 = 0.f, a2 = 0.f, a3 = 0.f;
        int i = b + half, e = b + dg;
        for (; i + 8 <= e + half; i += 8) {   // halves interleave: covers [i-half, i-half+8)
            int2 r0 = csr[i], r1 = csr[i + 2], r2 = csr[i + 4], r3 = csr[i + 6];
            a0 = fmaf(__int_as_float(r0.y), hr[(size_t)r0.x * 32 + j], a0);
            a1 = fmaf(__int_as_float(r1.y), hr[(size_t)r1.x * 32 + j], a1);
            a2 = fmaf(__int_as_float(r2.y), hr[(size_t)r2.x * 32 + j], a2);
            a3 = fmaf(__int_as_float(r3.y), hr[(size_t)r3.x * 32 + j], a3);
        }
        for (; i < e; i += 2) {
            int2 r = csr[i];
            a0 = fmaf(__int_as_float(r.y), hr[(size_t)r.x * 32 + j], a0);
        }
        float acc = (a0 + a1) + (a2 + a3);
        acc += __shfl_xor(acc, 32);
        if (half == 0) {
            float inv = 1.0f / fmaxf((float)dg, 1.0f);
            out[(size_t)n * 32 + j] = acc * inv + hro[(size_t)n * 32 + j];
        }
    }
}

extern "C" void kernel_launch(void* const* d_in, const int* in_sizes, int n_in,
                              void* d_out, int out_size, void* d_ws, size_t ws_size,
                              hipStream_t stream) {
    const float* x      = (const float*)d_in[0];
    const void*  ei_raw = d_in[1];
    const float* ea     = (const float*)d_in[2];
    const float* Wrel1  = (const float*)d_in[3];
    const float* brel1  = (const float*)d_in[4];
    const float* Wroot1 = (const float*)d_in[5];
    const float* Wrel2  = (const float*)d_in[6];
    const float* brel2  = (const float*)d_in[7];
    const float* Wroot2 = (const float*)d_in[8];
    float* out = (float*)d_out;

    const int N = in_sizes[0] / NF;     // 100000
    const int E = in_sizes[2];          // 1000000
    const int nbuck = (N + 127) >> 7;

    // workspace layout
    int2*  csr    = (int2*)d_ws;                    // E
    int*   deg    = (int*)(csr + E);                // N
    int*   base   = deg + N;                        // N
    int*   cursor = base + N;                       // N
    int*   bcur   = cursor + N;                     // nbuck
    int*   bsums  = bcur + nbuck;                   // 256
    int*   flag   = bsums + 256;                    // 1 (+3 pad)
    float* aggm   = (float*)(flag + 4);             // N*64 (build tmp overlaps here)
    float* hr     = aggm + (size_t)N * 64;          // N*32
    float* hro    = hr + (size_t)N * 32;            // N*32
    // CSR-build temporaries overlap aggm (dead until gather1):
    int2*  tmpv   = (int2*)aggm;                    // E
    int*   tmpd   = (int*)(tmpv + E);               // E

    const int nb1 = (N + 1023) / 1024;

    hipMemsetAsync(deg, 0, (size_t)N * sizeof(int), stream);
    detect_i64<<<1, 256, 0, stream>>>((const unsigned*)ei_raw, flag, E);
    hist<<<(E + 255) / 256, 256, 0, stream>>>(ei_raw, flag, deg, E);
    scan_k1<<<nb1, 1024, 0, stream>>>(deg, base, bsums, N);
    scan_k2<<<1, 256, 0, stream>>>(bsums, nb1);
    scan_k3<<<nb1, 1024, 0, stream>>>(base, bsums, cursor, N);
    binit<<<(nbuck + 255) / 256, 256, 0, stream>>>(base, bcur, nbuck);
    pass1_bucket<<<(E + 255) / 256, 256, 0, stream>>>(ei_raw, flag, ea, bcur, tmpv, tmpd, E);
    pass2_place<<<(E + 255) / 256, 256, 0, stream>>>(tmpv, tmpd, cursor, csr, E);

    gather1<<<2048, 256, 0, stream>>>(x, csr, base, deg, aggm, N);
    nodeAB<<<2048, 256, 0, stream>>>(x, aggm, Wrel1, brel1, Wroot1,
                                     Wrel2, brel2, Wroot2, hr, hro, N);
    gather2<<<2048, 256, 0, stream>>>(hr, hro, csr, base, deg, out, N);
}

// Round 6
// 321.546 us; speedup vs baseline: 1.8039x; 1.8039x over previous
//
#include <hip/hip_runtime.h>
#include <hip/hip_bf16.h>

// GraphConv x2 via dst-sorted CSR gather (no float atomics):
//   gather1: aggm = mean_e w*x[src]
//   nodeA:   h  = sigmoid(aggm@Wrel1^T + b1 + x@Wroot1^T)   (reg-resident W)
//   nodeB:   hr = h@Wrel2^T ; hro = h@Wroot2^T + b2          (reg-resident W)
//   gather2: out = mean_e w*hr[src] + hro
// CSR build: hist -> scan -> single-pass atomic placement (bucketed 2-pass
// regressed 3x: 782 hot bucket cursors serialize; 100k cursors don't).

#define NF 64

// ---------------- dtype detection (int64 vs int32 edge_index) ---------------
__global__ void detect_i64(const unsigned* __restrict__ raw, int* __restrict__ flag, int E) {
    __shared__ unsigned red[256];
    unsigned v = 0;
    int lim = (E < 4096) ? E : 4096;
    for (int i = threadIdx.x; i < lim; i += 256) v |= raw[2 * i + 1];
    red[threadIdx.x] = v;
    __syncthreads();
    for (int s = 128; s > 0; s >>= 1) {
        if (threadIdx.x < s) red[threadIdx.x] |= red[threadIdx.x + s];
        __syncthreads();
    }
    if (threadIdx.x == 0) *flag = (red[0] == 0) ? 1 : 0;  // high dwords zero => int64
}

// ---------------- histogram of dst ------------------------------------------
__global__ __launch_bounds__(256) void hist(const void* __restrict__ raw,
                                            const int* __restrict__ flag,
                                            int* __restrict__ deg, int E) {
    int e = blockIdx.x * blockDim.x + threadIdx.x;
    if (e >= E) return;
    int d;
    if (*flag) d = (int)__builtin_nontemporal_load(((const long long*)raw) + E + e);
    else       d = __builtin_nontemporal_load(((const int*)raw) + E + e);
    atomicAdd(&deg[d], 1);
}

// ---------------- exclusive scan (3 kernels) ---------------------------------
__global__ __launch_bounds__(1024) void scan_k1(const int* __restrict__ deg,
                                                int* __restrict__ base,
                                                int* __restrict__ bsums, int N) {
    __shared__ int tmp[1024];
    int tid = threadIdx.x;
    int i = blockIdx.x * 1024 + tid;
    int v = (i < N) ? deg[i] : 0;
    tmp[tid] = v;
    __syncthreads();
    for (int off = 1; off < 1024; off <<= 1) {
        int t = (tid >= off) ? tmp[tid - off] : 0;
        __syncthreads();
        tmp[tid] += t;
        __syncthreads();
    }
    if (i < N) base[i] = tmp[tid] - v;
    if (tid == 1023) bsums[blockIdx.x] = tmp[tid];
}

__global__ __launch_bounds__(256) void scan_k2(int* __restrict__ bsums, int nb) {
    __shared__ int tmp[256];
    int tid = threadIdx.x;
    int v = (tid < nb) ? bsums[tid] : 0;
    tmp[tid] = v;
    __syncthreads();
    for (int off = 1; off < 256; off <<= 1) {
        int t = (tid >= off) ? tmp[tid - off] : 0;
        __syncthreads();
        tmp[tid] += t;
        __syncthreads();
    }
    if (tid < nb) bsums[tid] = tmp[tid] - v;
}

__global__ __launch_bounds__(1024) void scan_k3(int* __restrict__ base,
                                                const int* __restrict__ bsums,
                                                int* __restrict__ cursor, int N) {
    int i = blockIdx.x * 1024 + threadIdx.x;
    if (i >= N) return;
    int b = base[i] + bsums[blockIdx.x];
    base[i] = b;
    cursor[i] = b;
}

// ---------------- fill CSR slots (single pass) -------------------------------
__global__ __launch_bounds__(256) void fill_csr(const void* __restrict__ raw,
                                                const int* __restrict__ flag,
                                                const float* __restrict__ ea,
                                                int* __restrict__ cursor,
                                                int2* __restrict__ csr, int E) {
    int e = blockIdx.x * blockDim.x + threadIdx.x;
    if (e >= E) return;
    int s, d;
    if (*flag) {
        const long long* p = (const long long*)raw;
        s = (int)__builtin_nontemporal_load(p + e);
        d = (int)__builtin_nontemporal_load(p + E + e);
    } else {
        const int* p = (const int*)raw;
        s = __builtin_nontemporal_load(p + e);
        d = __builtin_nontemporal_load(p + E + e);
    }
    float w = __builtin_nontemporal_load(ea + e);
    int slot = atomicAdd(&cursor[d], 1);
    csr[slot] = make_int2(s, __float_as_int(w));
}

// ---------------- gather1: aggm[n] = (sum_e w*x[src])/max(deg,1) -------------
__global__ __launch_bounds__(256) void gather1(
    const float* __restrict__ x, const int2* __restrict__ csr,
    const int* __restrict__ base, const int* __restrict__ deg,
    float* __restrict__ aggm, int N)
{
    int lane = threadIdx.x & 63;
    int wid = blockIdx.x * 4 + (threadIdx.x >> 6);
    int stride = gridDim.x * 4;
    for (int n = wid; n < N; n += stride) {
        int b = __builtin_amdgcn_readfirstlane(base[n]);
        int dg = __builtin_amdgcn_readfirstlane(deg[n]);
        float acc0 = 0.f, acc1 = 0.f, acc2 = 0.f, acc3 = 0.f;
        int i = b, e = b + dg;
        for (; i + 8 <= e; i += 8) {
            int2 r0 = csr[i], r1 = csr[i + 1], r2 = csr[i + 2], r3 = csr[i + 3];
            int2 r4 = csr[i + 4], r5 = csr[i + 5], r6 = csr[i + 6], r7 = csr[i + 7];
            float v0 = x[(size_t)r0.x * 64 + lane];
            float v1 = x[(size_t)r1.x * 64 + lane];
            float v2 = x[(size_t)r2.x * 64 + lane];
            float v3 = x[(size_t)r3.x * 64 + lane];
            float v4 = x[(size_t)r4.x * 64 + lane];
            float v5 = x[(size_t)r5.x * 64 + lane];
            float v6 = x[(size_t)r6.x * 64 + lane];
            float v7 = x[(size_t)r7.x * 64 + lane];
            acc0 = fmaf(__int_as_float(r0.y), v0, acc0);
            acc1 = fmaf(__int_as_float(r1.y), v1, acc1);
            acc2 = fmaf(__int_as_float(r2.y), v2, acc2);
            acc3 = fmaf(__int_as_float(r3.y), v3, acc3);
            acc0 = fmaf(__int_as_float(r4.y), v4, acc0);
            acc1 = fmaf(__int_as_float(r5.y), v5, acc1);
            acc2 = fmaf(__int_as_float(r6.y), v6, acc2);
            acc3 = fmaf(__int_as_float(r7.y), v7, acc3);
        }
        for (; i + 4 <= e; i += 4) {
            int2 r0 = csr[i], r1 = csr[i + 1], r2 = csr[i + 2], r3 = csr[i + 3];
            acc0 = fmaf(__int_as_float(r0.y), x[(size_t)r0.x * 64 + lane], acc0);
            acc1 = fmaf(__int_as_float(r1.y), x[(size_t)r1.x * 64 + lane], acc1);
            acc2 = fmaf(__int_as_float(r2.y), x[(size_t)r2.x * 64 + lane], acc2);
            acc3 = fmaf(__int_as_float(r3.y), x[(size_t)r3.x * 64 + lane], acc3);
        }
        for (; i < e; ++i) {
            int2 r = csr[i];
            acc0 = fmaf(__int_as_float(r.y), x[(size_t)r.x * 64 + lane], acc0);
        }
        float inv = 1.0f / fmaxf((float)dg, 1.0f);
        aggm[(size_t)n * 64 + lane] = ((acc0 + acc1) + (acc2 + acc3)) * inv;
    }
}

// ---------------- nodeA: h = sigmoid(aggm@Wrel1^T + b1 + x@Wroot1^T) ---------
// lane = output feature; weight rows FORCED register-resident via
// __launch_bounds__(256,1) (round-3/4 VGPR=72 showed the compiler re-loading
// weights from L1 every iteration -> L1-port-bound, grid-invariant 81us).
__global__ __launch_bounds__(256, 1) void nodeA(
    const float* __restrict__ x, const float* __restrict__ aggm,
    const float* __restrict__ Wrel1, const float* __restrict__ brel1,
    const float* __restrict__ Wroot1, float* __restrict__ h, int N)
{
    int lane = threadIdx.x & 63;
    float4 wr[16], wo[16];
#pragma unroll
    for (int c = 0; c < 16; ++c) {
        wr[c] = *(const float4*)(Wrel1 + (size_t)lane * 64 + 4 * c);
        wo[c] = *(const float4*)(Wroot1 + (size_t)lane * 64 + 4 * c);
    }
    float bias = brel1[lane];
    int wid = blockIdx.x * 4 + (threadIdx.x >> 6);
    int stride = gridDim.x * 4;
    for (int n0 = wid * 2; n0 < N; n0 += stride * 2) {
        int nA = __builtin_amdgcn_readfirstlane(n0);
        bool hasB = (n0 + 1) < N;
        int nB = __builtin_amdgcn_readfirstlane(hasB ? n0 + 1 : n0);
        const float* ar0 = aggm + (size_t)nA * 64;
        const float* xr0 = x + (size_t)nA * 64;
        const float* ar1 = aggm + (size_t)nB * 64;
        const float* xr1 = x + (size_t)nB * 64;
        float accr0 = bias, acco0 = 0.f, accr1 = bias, acco1 = 0.f;
#pragma unroll
        for (int c = 0; c < 16; ++c) {
            float4 a0 = *(const float4*)(ar0 + 4 * c);
            float4 x0 = *(const float4*)(xr0 + 4 * c);
            float4 a1 = *(const float4*)(ar1 + 4 * c);
            float4 x1 = *(const float4*)(xr1 + 4 * c);
            accr0 = fmaf(a0.x, wr[c].x, accr0); accr1 = fmaf(a1.x, wr[c].x, accr1);
            accr0 = fmaf(a0.y, wr[c].y, accr0); accr1 = fmaf(a1.y, wr[c].y, accr1);
            accr0 = fmaf(a0.z, wr[c].z, accr0); accr1 = fmaf(a1.z, wr[c].z, accr1);
            accr0 = fmaf(a0.w, wr[c].w, accr0); accr1 = fmaf(a1.w, wr[c].w, accr1);
            acco0 = fmaf(x0.x, wo[c].x, acco0); acco1 = fmaf(x1.x, wo[c].x, acco1);
            acco0 = fmaf(x0.y, wo[c].y, acco0); acco1 = fmaf(x1.y, wo[c].y, acco1);
            acco0 = fmaf(x0.z, wo[c].z, acco0); acco1 = fmaf(x1.z, wo[c].z, acco1);
            acco0 = fmaf(x0.w, wo[c].w, acco0); acco1 = fmaf(x1.w, wo[c].w, acco1);
        }
        float h0 = 1.0f / (1.0f + __expf(-(accr0 + acco0)));
        float h1 = 1.0f / (1.0f + __expf(-(accr1 + acco1)));
        h[(size_t)nA * 64 + lane] = h0;
        if (hasB) h[(size_t)nB * 64 + lane] = h1;
    }
}

// ---------------- nodeB: hr = h@Wrel2^T ; hro = h@Wroot2^T + b2 --------------
// lanes 0..31 -> hr row j=lane; lanes 32..63 -> hro row j=lane-32.
__global__ __launch_bounds__(256, 1) void nodeB(
    const float* __restrict__ h, const float* __restrict__ Wrel2,
    const float* __restrict__ brel2, const float* __restrict__ Wroot2,
    float* __restrict__ hr, float* __restrict__ hro, int N)
{
    int lane = threadIdx.x & 63;
    int j = lane & 31;
    bool isRel = lane < 32;
    const float* wsrc = (isRel ? Wrel2 : Wroot2) + (size_t)j * 64;
    float4 w[16];
#pragma unroll
    for (int c = 0; c < 16; ++c) w[c] = *(const float4*)(wsrc + 4 * c);
    float bias = isRel ? 0.f : brel2[j];
    float* dstbuf = isRel ? hr : hro;

    int wid = blockIdx.x * 4 + (threadIdx.x >> 6);
    int stride = gridDim.x * 4;
    for (int n0 = wid * 2; n0 < N; n0 += stride * 2) {
        int nA = __builtin_amdgcn_readfirstlane(n0);
        bool hasB = (n0 + 1) < N;
        int nB = __builtin_amdgcn_readfirstlane(hasB ? n0 + 1 : n0);
        const float* h0 = h + (size_t)nA * 64;
        const float* h1 = h + (size_t)nB * 64;
        float acc0 = bias, acc1 = bias;
#pragma unroll
        for (int c = 0; c < 16; ++c) {
            float4 v0 = *(const float4*)(h0 + 4 * c);
            float4 v1 = *(const float4*)(h1 + 4 * c);
            acc0 = fmaf(v0.x, w[c].x, acc0); acc1 = fmaf(v1.x, w[c].x, acc1);
            acc0 = fmaf(v0.y, w[c].y, acc0); acc1 = fmaf(v1.y, w[c].y, acc1);
            acc0 = fmaf(v0.z, w[c].z, acc0); acc1 = fmaf(v1.z, w[c].z, acc1);
            acc0 = fmaf(v0.w, w[c].w, acc0); acc1 = fmaf(v1.w, w[c].w, acc1);
        }
        dstbuf[(size_t)nA * 32 + j] = acc0;
        if (hasB) dstbuf[(size_t)nB * 32 + j] = acc1;
    }
}

// ---------------- gather2 + epilogue: out = agg2/deg + hro -------------------
__global__ __launch_bounds__(256) void gather2(
    const float* __restrict__ hr, const float* __restrict__ hro,
    const int2* __restrict__ csr, const int* __restrict__ base,
    const int* __restrict__ deg, float* __restrict__ out, int N)
{
    int lane = threadIdx.x & 63;
    int j = lane & 31, half = lane >> 5;
    int wid = blockIdx.x * 4 + (threadIdx.x >> 6);
    int stride = gridDim.x * 4;
    for (int n = wid; n < N; n += stride) {
        int b = __builtin_amdgcn_readfirstlane(base[n]);
        int dg = __builtin_amdgcn_readfirstlane(deg[n]);
        float a0 = 0.f, a1 = 0.f, a2 = 0.f, a3 = 0.f;
        int i = b + half, e = b + dg;
        for (; i + 8 <= e + half; i += 8) {
            int2 r0 = csr[i], r1 = csr[i + 2], r2 = csr[i + 4], r3 = csr[i + 6];
            a0 = fmaf(__int_as_float(r0.y), hr[(size_t)r0.x * 32 + j], a0);
            a1 = fmaf(__int_as_float(r1.y), hr[(size_t)r1.x * 32 + j], a1);
            a2 = fmaf(__int_as_float(r2.y), hr[(size_t)r2.x * 32 + j], a2);
            a3 = fmaf(__int_as_float(r3.y), hr[(size_t)r3.x * 32 + j], a3);
        }
        for (; i < e; i += 2) {
            int2 r = csr[i];
            a0 = fmaf(__int_as_float(r.y), hr[(size_t)r.x * 32 + j], a0);
        }
        float acc = (a0 + a1) + (a2 + a3);
        acc += __shfl_xor(acc, 32);
        if (half == 0) {
            float inv = 1.0f / fmaxf((float)dg, 1.0f);
            out[(size_t)n * 32 + j] = acc * inv + hro[(size_t)n * 32 + j];
        }
    }
}

extern "C" void kernel_launch(void* const* d_in, const int* in_sizes, int n_in,
                              void* d_out, int out_size, void* d_ws, size_t ws_size,
                              hipStream_t stream) {
    const float* x      = (const float*)d_in[0];
    const void*  ei_raw = d_in[1];
    const float* ea     = (const float*)d_in[2];
    const float* Wrel1  = (const float*)d_in[3];
    const float* brel1  = (const float*)d_in[4];
    const float* Wroot1 = (const float*)d_in[5];
    const float* Wrel2  = (const float*)d_in[6];
    const float* brel2  = (const float*)d_in[7];
    const float* Wroot2 = (const float*)d_in[8];
    float* out = (float*)d_out;

    const int N = in_sizes[0] / NF;     // 100000
    const int E = in_sizes[2];          // 1000000

    // workspace layout
    int2*  csr    = (int2*)d_ws;                    // E
    int*   deg    = (int*)(csr + E);                // N
    int*   base   = deg + N;                        // N
    int*   cursor = base + N;                       // N
    int*   bsums  = cursor + N;                     // 256
    int*   flag   = bsums + 256;                    // 1 (+3 pad)
    float* aggm   = (float*)(flag + 4);             // N*64 ; reused as hr|hro
    float* h      = aggm + (size_t)N * 64;          // N*64
    float* hr     = aggm;                           // N*32 (aggm dead after nodeA)
    float* hro    = aggm + (size_t)N * 32;          // N*32

    const int nb1 = (N + 1023) / 1024;

    hipMemsetAsync(deg, 0, (size_t)N * sizeof(int), stream);
    detect_i64<<<1, 256, 0, stream>>>((const unsigned*)ei_raw, flag, E);
    hist<<<(E + 255) / 256, 256, 0, stream>>>(ei_raw, flag, deg, E);
    scan_k1<<<nb1, 1024, 0, stream>>>(deg, base, bsums, N);
    scan_k2<<<1, 256, 0, stream>>>(bsums, nb1);
    scan_k3<<<nb1, 1024, 0, stream>>>(base, bsums, cursor, N);
    fill_csr<<<(E + 255) / 256, 256, 0, stream>>>(ei_raw, flag, ea, cursor, csr, E);

    gather1<<<2048, 256, 0, stream>>>(x, csr, base, deg, aggm, N);
    nodeA<<<2048, 256, 0, stream>>>(x, aggm, Wrel1, brel1, Wroot1, h, N);
    nodeB<<<2048, 256, 0, stream>>>(h, Wrel2, brel2, Wroot2, hr, hro, N);
    gather2<<<2048, 256, 0, stream>>>(hr, hro, csr, base, deg, out, N);
}

// Round 7
// 314.871 us; speedup vs baseline: 1.8422x; 1.0212x over previous
//
#include <hip/hip_runtime.h>
#include <hip/hip_bf16.h>

// GraphConv x2 via dst-sorted CSR gather (no float atomics):
//   gather1: aggm = mean_e w*x[src]
//   nodeA:   h  = sigmoid(aggm@Wrel1^T + b1 + x@Wroot1^T)   (reg-PINNED W)
//   nodeB:   hr = h@Wrel2^T ; hro = h@Wroot2^T + b2          (reg-PINNED W)
//   gather2: out = mean_e w*hr[src] + hro
// CSR build: hist -> scan -> 7 dst-range passes (one launch) so csr lines
// fill within a short time window -> L2 merges writes (was 8x write amp).

#define NF 64

// ---------------- dtype detection (int64 vs int32 edge_index) ---------------
__global__ void detect_i64(const unsigned* __restrict__ raw, int* __restrict__ flag, int E) {
    __shared__ unsigned red[256];
    unsigned v = 0;
    int lim = (E < 4096) ? E : 4096;
    for (int i = threadIdx.x; i < lim; i += 256) v |= raw[2 * i + 1];
    red[threadIdx.x] = v;
    __syncthreads();
    for (int s = 128; s > 0; s >>= 1) {
        if (threadIdx.x < s) red[threadIdx.x] |= red[threadIdx.x + s];
        __syncthreads();
    }
    if (threadIdx.x == 0) *flag = (red[0] == 0) ? 1 : 0;  // high dwords zero => int64
}

// ---------------- histogram of dst + materialize dst32 -----------------------
__global__ __launch_bounds__(256) void hist(const void* __restrict__ raw,
                                            const int* __restrict__ flag,
                                            int* __restrict__ deg,
                                            int* __restrict__ dst32, int E) {
    int e = blockIdx.x * blockDim.x + threadIdx.x;
    if (e >= E) return;
    int d;
    if (*flag) d = (int)__builtin_nontemporal_load(((const long long*)raw) + E + e);
    else       d = __builtin_nontemporal_load(((const int*)raw) + E + e);
    dst32[e] = d;
    atomicAdd(&deg[d], 1);
}

// ---------------- exclusive scan (3 kernels) ---------------------------------
__global__ __launch_bounds__(1024) void scan_k1(const int* __restrict__ deg,
                                                int* __restrict__ base,
                                                int* __restrict__ bsums, int N) {
    __shared__ int tmp[1024];
    int tid = threadIdx.x;
    int i = blockIdx.x * 1024 + tid;
    int v = (i < N) ? deg[i] : 0;
    tmp[tid] = v;
    __syncthreads();
    for (int off = 1; off < 1024; off <<= 1) {
        int t = (tid >= off) ? tmp[tid - off] : 0;
        __syncthreads();
        tmp[tid] += t;
        __syncthreads();
    }
    if (i < N) base[i] = tmp[tid] - v;
    if (tid == 1023) bsums[blockIdx.x] = tmp[tid];
}

__global__ __launch_bounds__(256) void scan_k2(int* __restrict__ bsums, int nb) {
    __shared__ int tmp[256];
    int tid = threadIdx.x;
    int v = (tid < nb) ? bsums[tid] : 0;
    tmp[tid] = v;
    __syncthreads();
    for (int off = 1; off < 256; off <<= 1) {
        int t = (tid >= off) ? tmp[tid - off] : 0;
        __syncthreads();
        tmp[tid] += t;
        __syncthreads();
    }
    if (tid < nb) bsums[tid] = tmp[tid] - v;
}

__global__ __launch_bounds__(1024) void scan_k3(int* __restrict__ base,
                                                const int* __restrict__ bsums,
                                                int* __restrict__ cursor, int N) {
    int i = blockIdx.x * 1024 + threadIdx.x;
    if (i >= N) return;
    int b = base[i] + bsums[blockIdx.x];
    base[i] = b;
    cursor[i] = b;
}

// ---------------- fill CSR: 7 dst-range passes in one launch ------------------
// pass = blockIdx.x / bpp; only edges with dst>>14 == pass are placed. Blocks
// dispatch roughly in order, so each ~1.3MB csr window gets its writes
// temporally clustered -> L2 merges 8B stores into full lines.
__global__ __launch_bounds__(256) void fill_pass(
    const void* __restrict__ raw, const int* __restrict__ flag,
    const float* __restrict__ ea, const int* __restrict__ dst32,
    int* __restrict__ cursor, int2* __restrict__ csr, int E, int bpp)
{
    int pass = blockIdx.x / bpp;
    int e = (blockIdx.x - pass * bpp) * 256 + threadIdx.x;
    if (e >= E) return;
    int d = dst32[e];
    if ((d >> 14) != pass) return;
    int s;
    if (*flag) s = (int)((const long long*)raw)[e];
    else       s = ((const int*)raw)[e];
    float w = ea[e];
    int slot = atomicAdd(&cursor[d], 1);
    csr[slot] = make_int2(s, __float_as_int(w));
}

// ---------------- gather1: aggm[n] = (sum_e w*x[src])/max(deg,1) -------------
__global__ __launch_bounds__(256) void gather1(
    const float* __restrict__ x, const int2* __restrict__ csr,
    const int* __restrict__ base, const int* __restrict__ deg,
    float* __restrict__ aggm, int N)
{
    int lane = threadIdx.x & 63;
    int wid = blockIdx.x * 4 + (threadIdx.x >> 6);
    int stride = gridDim.x * 4;
    for (int n = wid; n < N; n += stride) {
        int b = __builtin_amdgcn_readfirstlane(base[n]);
        int dg = __builtin_amdgcn_readfirstlane(deg[n]);
        float acc0 = 0.f, acc1 = 0.f, acc2 = 0.f, acc3 = 0.f;
        int i = b, e = b + dg;
        for (; i + 8 <= e; i += 8) {
            int2 r0 = csr[i], r1 = csr[i + 1], r2 = csr[i + 2], r3 = csr[i + 3];
            int2 r4 = csr[i + 4], r5 = csr[i + 5], r6 = csr[i + 6], r7 = csr[i + 7];
            float v0 = x[(size_t)r0.x * 64 + lane];
            float v1 = x[(size_t)r1.x * 64 + lane];
            float v2 = x[(size_t)r2.x * 64 + lane];
            float v3 = x[(size_t)r3.x * 64 + lane];
            float v4 = x[(size_t)r4.x * 64 + lane];
            float v5 = x[(size_t)r5.x * 64 + lane];
            float v6 = x[(size_t)r6.x * 64 + lane];
            float v7 = x[(size_t)r7.x * 64 + lane];
            acc0 = fmaf(__int_as_float(r0.y), v0, acc0);
            acc1 = fmaf(__int_as_float(r1.y), v1, acc1);
            acc2 = fmaf(__int_as_float(r2.y), v2, acc2);
            acc3 = fmaf(__int_as_float(r3.y), v3, acc3);
            acc0 = fmaf(__int_as_float(r4.y), v4, acc0);
            acc1 = fmaf(__int_as_float(r5.y), v5, acc1);
            acc2 = fmaf(__int_as_float(r6.y), v6, acc2);
            acc3 = fmaf(__int_as_float(r7.y), v7, acc3);
        }
        for (; i + 4 <= e; i += 4) {
            int2 r0 = csr[i], r1 = csr[i + 1], r2 = csr[i + 2], r3 = csr[i + 3];
            acc0 = fmaf(__int_as_float(r0.y), x[(size_t)r0.x * 64 + lane], acc0);
            acc1 = fmaf(__int_as_float(r1.y), x[(size_t)r1.x * 64 + lane], acc1);
            acc2 = fmaf(__int_as_float(r2.y), x[(size_t)r2.x * 64 + lane], acc2);
            acc3 = fmaf(__int_as_float(r3.y), x[(size_t)r3.x * 64 + lane], acc3);
        }
        for (; i < e; ++i) {
            int2 r = csr[i];
            acc0 = fmaf(__int_as_float(r.y), x[(size_t)r.x * 64 + lane], acc0);
        }
        float inv = 1.0f / fmaxf((float)dg, 1.0f);
        aggm[(size_t)n * 64 + lane] = ((acc0 + acc1) + (acc2 + acc3)) * inv;
    }
}

// ---------------- nodeA: h = sigmoid(aggm@Wrel1^T + b1 + x@Wroot1^T) ---------
// lane = output feature. Weights loaded once and PINNED in VGPRs via empty
// asm (prevents LLVM rematerializing the loads -> was L1-gather-bound 80us).
__global__ __launch_bounds__(256, 1) void nodeA(
    const float* __restrict__ x, const float* __restrict__ aggm,
    const float* __restrict__ Wrel1, const float* __restrict__ brel1,
    const float* __restrict__ Wroot1, float* __restrict__ h, int N)
{
    int lane = threadIdx.x & 63;
    float4 wr[16], wo[16];
#pragma unroll
    for (int c = 0; c < 16; ++c) {
        wr[c] = *(const float4*)(Wrel1 + (size_t)lane * 64 + 4 * c);
        wo[c] = *(const float4*)(Wroot1 + (size_t)lane * 64 + 4 * c);
    }
#pragma unroll
    for (int c = 0; c < 16; ++c) {
        asm volatile("" : "+v"(wr[c].x), "+v"(wr[c].y), "+v"(wr[c].z), "+v"(wr[c].w));
        asm volatile("" : "+v"(wo[c].x), "+v"(wo[c].y), "+v"(wo[c].z), "+v"(wo[c].w));
    }
    float bias = brel1[lane];
    int wid = blockIdx.x * 4 + (threadIdx.x >> 6);
    int stride = gridDim.x * 4;
    for (int n0 = wid * 2; n0 < N; n0 += stride * 2) {
        int nA = __builtin_amdgcn_readfirstlane(n0);
        bool hasB = (n0 + 1) < N;
        int nB = __builtin_amdgcn_readfirstlane(hasB ? n0 + 1 : n0);
        const float* ar0 = aggm + (size_t)nA * 64;
        const float* xr0 = x + (size_t)nA * 64;
        const float* ar1 = aggm + (size_t)nB * 64;
        const float* xr1 = x + (size_t)nB * 64;
        float accr0 = bias, acco0 = 0.f, accr1 = bias, acco1 = 0.f;
#pragma unroll
        for (int c = 0; c < 16; ++c) {
            float4 a0 = *(const float4*)(ar0 + 4 * c);
            float4 x0 = *(const float4*)(xr0 + 4 * c);
            float4 a1 = *(const float4*)(ar1 + 4 * c);
            float4 x1 = *(const float4*)(xr1 + 4 * c);
            accr0 = fmaf(a0.x, wr[c].x, accr0); accr1 = fmaf(a1.x, wr[c].x, accr1);
            accr0 = fmaf(a0.y, wr[c].y, accr0); accr1 = fmaf(a1.y, wr[c].y, accr1);
            accr0 = fmaf(a0.z, wr[c].z, accr0); accr1 = fmaf(a1.z, wr[c].z, accr1);
            accr0 = fmaf(a0.w, wr[c].w, accr0); accr1 = fmaf(a1.w, wr[c].w, accr1);
            acco0 = fmaf(x0.x, wo[c].x, acco0); acco1 = fmaf(x1.x, wo[c].x, acco1);
            acco0 = fmaf(x0.y, wo[c].y, acco0); acco1 = fmaf(x1.y, wo[c].y, acco1);
            acco0 = fmaf(x0.z, wo[c].z, acco0); acco1 = fmaf(x1.z, wo[c].z, acco1);
            acco0 = fmaf(x0.w, wo[c].w, acco0); acco1 = fmaf(x1.w, wo[c].w, acco1);
        }
        float h0 = 1.0f / (1.0f + __expf(-(accr0 + acco0)));
        float h1 = 1.0f / (1.0f + __expf(-(accr1 + acco1)));
        h[(size_t)nA * 64 + lane] = h0;
        if (hasB) h[(size_t)nB * 64 + lane] = h1;
    }
}

// ---------------- nodeB: hr = h@Wrel2^T ; hro = h@Wroot2^T + b2 --------------
// lanes 0..31 -> hr row j=lane; lanes 32..63 -> hro row j=lane-32.
__global__ __launch_bounds__(256, 1) void nodeB(
    const float* __restrict__ h, const float* __restrict__ Wrel2,
    const float* __restrict__ brel2, const float* __restrict__ Wroot2,
    float* __restrict__ hr, float* __restrict__ hro, int N)
{
    int lane = threadIdx.x & 63;
    int j = lane & 31;
    bool isRel = lane < 32;
    const float* wsrc = (isRel ? Wrel2 : Wroot2) + (size_t)j * 64;
    float4 w[16];
#pragma unroll
    for (int c = 0; c < 16; ++c) w[c] = *(const float4*)(wsrc + 4 * c);
#pragma unroll
    for (int c = 0; c < 16; ++c) {
        asm volatile("" : "+v"(w[c].x), "+v"(w[c].y), "+v"(w[c].z), "+v"(w[c].w));
    }
    float bias = isRel ? 0.f : brel2[j];
    float* dstbuf = isRel ? hr : hro;

    int wid = blockIdx.x * 4 + (threadIdx.x >> 6);
    int stride = gridDim.x * 4;
    for (int n0 = wid * 2; n0 < N; n0 += stride * 2) {
        int nA = __builtin_amdgcn_readfirstlane(n0);
        bool hasB = (n0 + 1) < N;
        int nB = __builtin_amdgcn_readfirstlane(hasB ? n0 + 1 : n0);
        const float* h0 = h + (size_t)nA * 64;
        const float* h1 = h + (size_t)nB * 64;
        float acc0 = bias, acc1 = bias;
#pragma unroll
        for (int c = 0; c < 16; ++c) {
            float4 v0 = *(const float4*)(h0 + 4 * c);
            float4 v1 = *(const float4*)(h1 + 4 * c);
            acc0 = fmaf(v0.x, w[c].x, acc0); acc1 = fmaf(v1.x, w[c].x, acc1);
            acc0 = fmaf(v0.y, w[c].y, acc0); acc1 = fmaf(v1.y, w[c].y, acc1);
            acc0 = fmaf(v0.z, w[c].z, acc0); acc1 = fmaf(v1.z, w[c].z, acc1);
            acc0 = fmaf(v0.w, w[c].w, acc0); acc1 = fmaf(v1.w, w[c].w, acc1);
        }
        dstbuf[(size_t)nA * 32 + j] = acc0;
        if (hasB) dstbuf[(size_t)nB * 32 + j] = acc1;
    }
}

// ---------------- gather2 + epilogue: out = agg2/deg + hro -------------------
__global__ __launch_bounds__(256) void gather2(
    const float* __restrict__ hr, const float* __restrict__ hro,
    const int2* __restrict__ csr, const int* __restrict__ base,
    const int* __restrict__ deg, float* __restrict__ out, int N)
{
    int lane = threadIdx.x & 63;
    int j = lane & 31, half = lane >> 5;
    int wid = blockIdx.x * 4 + (threadIdx.x >> 6);
    int stride = gridDim.x * 4;
    for (int n = wid; n < N; n += stride) {
        int b = __builtin_amdgcn_readfirstlane(base[n]);
        int dg = __builtin_amdgcn_readfirstlane(deg[n]);
        float a0 = 0.f, a1 = 0.f, a2 = 0.f, a3 = 0.f;
        int i = b + half, e = b + dg;
        for (; i + 8 <= e + half; i += 8) {
            int2 r0 = csr[i], r1 = csr[i + 2], r2 = csr[i + 4], r3 = csr[i + 6];
            a0 = fmaf(__int_as_float(r0.y), hr[(size_t)r0.x * 32 + j], a0);
            a1 = fmaf(__int_as_float(r1.y), hr[(size_t)r1.x * 32 + j], a1);
            a2 = fmaf(__int_as_float(r2.y), hr[(size_t)r2.x * 32 + j], a2);
            a3 = fmaf(__int_as_float(r3.y), hr[(size_t)r3.x * 32 + j], a3);
        }
        for (; i < e; i += 2) {
            int2 r = csr[i];
            a0 = fmaf(__int_as_float(r.y), hr[(size_t)r.x * 32 + j], a0);
        }
        float acc = (a0 + a1) + (a2 + a3);
        acc += __shfl_xor(acc, 32);
        if (half == 0) {
            float inv = 1.0f / fmaxf((float)dg, 1.0f);
            out[(size_t)n * 32 + j] = acc * inv + hro[(size_t)n * 32 + j];
        }
    }
}

extern "C" void kernel_launch(void* const* d_in, const int* in_sizes, int n_in,
                              void* d_out, int out_size, void* d_ws, size_t ws_size,
                              hipStream_t stream) {
    const float* x      = (const float*)d_in[0];
    const void*  ei_raw = d_in[1];
    const float* ea     = (const float*)d_in[2];
    const float* Wrel1  = (const float*)d_in[3];
    const float* brel1  = (const float*)d_in[4];
    const float* Wroot1 = (const float*)d_in[5];
    const float* Wrel2  = (const float*)d_in[6];
    const float* brel2  = (const float*)d_in[7];
    const float* Wroot2 = (const float*)d_in[8];
    float* out = (float*)d_out;

    const int N = in_sizes[0] / NF;     // 100000
    const int E = in_sizes[2];          // 1000000

    // workspace layout
    int2*  csr    = (int2*)d_ws;                    // E (8 MB)
    int*   deg    = (int*)(csr + E);                // N
    int*   base   = deg + N;                        // N
    int*   cursor = base + N;                       // N
    int*   bsums  = cursor + N;                     // 256
    int*   flag   = bsums + 256;                    // 1 (+3 pad)
    int*   dst32  = flag + 4;                       // E (4 MB)
    float* aggm   = (float*)(dst32 + E);            // N*64 ; reused as hr|hro
    float* h      = aggm + (size_t)N * 64;          // N*64
    float* hr     = aggm;                           // N*32 (aggm dead after nodeA)
    float* hro    = aggm + (size_t)N * 32;          // N*32

    const int nb1 = (N + 1023) / 1024;
    const int bpp = (E + 255) / 256;                // blocks per pass
    const int npass = (N + 16383) >> 14;            // 7 for N=100000

    hipMemsetAsync(deg, 0, (size_t)N * sizeof(int), stream);
    detect_i64<<<1, 256, 0, stream>>>((const unsigned*)ei_raw, flag, E);
    hist<<<bpp, 256, 0, stream>>>(ei_raw, flag, deg, dst32, E);
    scan_k1<<<nb1, 1024, 0, stream>>>(deg, base, bsums, N);
    scan_k2<<<1, 256, 0, stream>>>(bsums, nb1);
    scan_k3<<<nb1, 1024, 0, stream>>>(base, bsums, cursor, N);
    fill_pass<<<npass * bpp, 256, 0, stream>>>(ei_raw, flag, ea, dst32, cursor, csr, E, bpp);

    gather1<<<2048, 256, 0, stream>>>(x, csr, base, deg, aggm, N);
    nodeA<<<2048, 256, 0, stream>>>(x, aggm, Wrel1, brel1, Wroot1, h, N);
    nodeB<<<2048, 256, 0, stream>>>(h, Wrel2, brel2, Wroot2, hr, hro, N);
    gather2<<<2048, 256, 0, stream>>>(hr, hro, csr, base, deg, out, N);
}